// Round 1
// baseline (188.218 us; speedup 1.0000x reference)
//
#include <hip/hip_runtime.h>
#include <stdint.h>

// ODE: y' = tanh(y@W1+b1)@W2+b2, dopri5 fixed-step, 20 steps, out every 4.
// One kernel: each wave owns 16 rows; all state in registers; weights as
// bf16 MFMA fragments in registers; C->A layout transpose via private
// swizzled LDS tile per wave.

typedef __attribute__((ext_vector_type(8))) short short8;   // 8 bf16 (4 VGPRs)
typedef __attribute__((ext_vector_type(4))) float f32x4;

union U8 { uint32_t u[4]; short8 s; };

__device__ __forceinline__ uint32_t cvt_pk_bf16(float a, float b){
    uint32_t r;
    asm("v_cvt_pk_bf16_f32 %0, %1, %2" : "=v"(r) : "v"(a), "v"(b));
    return r;
}

__device__ __forceinline__ float fast_tanh(float x){
    // tanh(x) = 1 - 2/(1+e^{2x});  v_exp_f32 computes 2^x
    float e = __builtin_amdgcn_exp2f(x * 2.885390081777927f);   // 2*log2(e)
    float r = __builtin_amdgcn_rcpf(1.0f + e);
    return __builtin_fmaf(-2.0f, r, 1.0f);
}

// One evaluation of f(z) for this wave's 16 rows.
// z, kout: C-layout register tiles, index i = q*4 + t  <->  element
//   (row = 4*g+q of the 16-row tile, col = m + 16*t), m=lane&15, g=lane>>4.
__device__ __forceinline__ void odef(
    const float (&z)[16], float (&kout)[16],
    const short8 (&w1f)[8][2], const short8 (&w2f)[4][4],
    const float (&b1v)[8], const float (&b2v)[4],
    float* __restrict__ ldsT, int m, int g)
{
    // ---- write z (C-layout) into swizzled [16][64] f32 tile ----
    #pragma unroll
    for (int q=0; q<4; ++q){
        int r = 4*g + q;
        #pragma unroll
        for (int t=0; t<4; ++t){
            int c = m + 16*t;
            ldsT[r*64 + (c ^ ((r&7)<<2))] = z[q*4+t];
        }
    }
    asm volatile("s_waitcnt lgkmcnt(0)" ::: "memory");

    // ---- read A-fragments of z: lane m gets row m, cols kc*32+8g..+7 ----
    short8 za[2];
    #pragma unroll
    for (int kc=0; kc<2; ++kc){
        const f32x4 v0 = *(const f32x4*)(ldsT + m*64 + ((kc*32 + 8*g + 0) ^ ((m&7)<<2)));
        const f32x4 v1 = *(const f32x4*)(ldsT + m*64 + ((kc*32 + 8*g + 4) ^ ((m&7)<<2)));
        U8 u;
        u.u[0] = cvt_pk_bf16(v0[0], v0[1]);
        u.u[1] = cvt_pk_bf16(v0[2], v0[3]);
        u.u[2] = cvt_pk_bf16(v1[0], v1[1]);
        u.u[3] = cvt_pk_bf16(v1[2], v1[3]);
        za[kc] = u.s;
    }

    // ---- layer 1: u = z@W1 + b1, h = tanh(u); write h into swizzled [16][128] ----
    #pragma unroll
    for (int nt=0; nt<8; ++nt){
        f32x4 acc = {b1v[nt], b1v[nt], b1v[nt], b1v[nt]};
        acc = __builtin_amdgcn_mfma_f32_16x16x32_bf16(za[0], w1f[nt][0], acc, 0,0,0);
        acc = __builtin_amdgcn_mfma_f32_16x16x32_bf16(za[1], w1f[nt][1], acc, 0,0,0);
        #pragma unroll
        for (int q=0; q<4; ++q){
            int r = 4*g + q, c = m + 16*nt;
            ldsT[r*128 + (c ^ ((r&7)<<2))] = fast_tanh(acc[q]);
        }
    }
    asm volatile("s_waitcnt lgkmcnt(0)" ::: "memory");

    // ---- read A-fragments of h ----
    short8 ha[4];
    #pragma unroll
    for (int kc=0; kc<4; ++kc){
        const f32x4 v0 = *(const f32x4*)(ldsT + m*128 + ((kc*32 + 8*g + 0) ^ ((m&7)<<2)));
        const f32x4 v1 = *(const f32x4*)(ldsT + m*128 + ((kc*32 + 8*g + 4) ^ ((m&7)<<2)));
        U8 u;
        u.u[0] = cvt_pk_bf16(v0[0], v0[1]);
        u.u[1] = cvt_pk_bf16(v0[2], v0[3]);
        u.u[2] = cvt_pk_bf16(v1[0], v1[1]);
        u.u[3] = cvt_pk_bf16(v1[2], v1[3]);
        ha[kc] = u.s;
    }

    // ---- layer 2: k = h@W2 + b2 ----
    #pragma unroll
    for (int nt=0; nt<4; ++nt){
        f32x4 acc = {b2v[nt], b2v[nt], b2v[nt], b2v[nt]};
        #pragma unroll
        for (int kc=0; kc<4; ++kc)
            acc = __builtin_amdgcn_mfma_f32_16x16x32_bf16(ha[kc], w2f[nt][kc], acc, 0,0,0);
        #pragma unroll
        for (int q=0; q<4; ++q) kout[q*4+nt] = acc[q];
    }
}

__global__ __launch_bounds__(256, 1)
void ode_dopri5_kernel(const float* __restrict__ init_pos,
                       const float* __restrict__ W1, const float* __restrict__ b1,
                       const float* __restrict__ W2, const float* __restrict__ b2,
                       float* __restrict__ out)
{
    __shared__ __align__(16) float lds_w[64*128 + 128*64];   // 64 KB (init only)
    __shared__ __align__(16) float lds_t[4][16*128];         // 8 KB per wave

    const int tid  = threadIdx.x;
    const int wave = tid >> 6;
    const int lane = tid & 63;
    const int m = lane & 15;
    const int g = lane >> 4;
    float* ldsT = lds_t[wave];

    // ---- stage weights (f32) into LDS, coalesced ----
    {
        const f32x4* s1 = (const f32x4*)W1;
        const f32x4* s2 = (const f32x4*)W2;
        f32x4* d = (f32x4*)lds_w;
        #pragma unroll
        for (int i=0; i<8; ++i) d[tid + 256*i]        = s1[tid + 256*i];
        #pragma unroll
        for (int i=0; i<8; ++i) d[2048 + tid + 256*i] = s2[tid + 256*i];
    }
    __syncthreads();

    // ---- build bf16 weight B-fragments in registers ----
    // B-frag slot r of lane-group g (for n-col = m+16*nt) holds W[kc*32+8g+r][n].
    // (Any consistent A/B k-slot bijection is correct; C/D layout is the measured one.)
    short8 w1f[8][2], w2f[4][4];
    #pragma unroll
    for (int nt=0; nt<8; ++nt)
        #pragma unroll
        for (int kc=0; kc<2; ++kc){
            U8 u;
            #pragma unroll
            for (int j=0; j<4; ++j){
                int k0 = kc*32 + 8*g + 2*j;
                u.u[j] = cvt_pk_bf16(lds_w[k0*128 + m + 16*nt],
                                     lds_w[(k0+1)*128 + m + 16*nt]);
            }
            w1f[nt][kc] = u.s;
        }
    #pragma unroll
    for (int nt=0; nt<4; ++nt)
        #pragma unroll
        for (int kc=0; kc<4; ++kc){
            U8 u;
            #pragma unroll
            for (int j=0; j<4; ++j){
                int k0 = kc*32 + 8*g + 2*j;
                u.u[j] = cvt_pk_bf16(lds_w[8192 + k0*64 + m + 16*nt],
                                     lds_w[8192 + (k0+1)*64 + m + 16*nt]);
            }
            w2f[nt][kc] = u.s;
        }

    float b1v[8], b2v[4];
    #pragma unroll
    for (int nt=0; nt<8; ++nt) b1v[nt] = b1[m + 16*nt];
    #pragma unroll
    for (int nt=0; nt<4; ++nt) b2v[nt] = b2[m + 16*nt];

    // ---- load this wave's 16 rows of y in C-layout ----
    const int row0 = (blockIdx.x*4 + wave) * 16;
    float y[16];
    #pragma unroll
    for (int q=0; q<4; ++q)
        #pragma unroll
        for (int t=0; t<4; ++t)
            y[q*4+t] = init_pos[(size_t)(row0 + 4*g + q)*64 + m + 16*t];

    // Dopri5 coefficients
    const float dt  = 0.05f;
    const float A21 = 0.2f;
    const float A31 = 0.075f,                 A32 = 0.225f;
    const float A41 = 44.f/45.f,  A42 = -56.f/15.f,    A43 = 32.f/9.f;
    const float A51 = 19372.f/6561.f, A52 = -25360.f/2187.f, A53 = 64448.f/6561.f, A54 = -212.f/729.f;
    const float A61 = 9017.f/3168.f,  A62 = -355.f/33.f,     A63 = 46732.f/5247.f, A64 = 49.f/176.f, A65 = -5103.f/18656.f;
    const float B1  = 35.f/384.f, B3 = 500.f/1113.f, B4 = 125.f/192.f, B5 = -2187.f/6784.f, B6 = 11.f/84.f;

    float k1[16], k2[16], k3[16], k4[16], k5[16], k6[16], z[16];

    for (int step=0; step<20; ++step){
        odef(y, k1, w1f, w2f, b1v, b2v, ldsT, m, g);
        #pragma unroll
        for (int i=0;i<16;++i) z[i] = y[i] + dt*(A21*k1[i]);
        odef(z, k2, w1f, w2f, b1v, b2v, ldsT, m, g);
        #pragma unroll
        for (int i=0;i<16;++i) z[i] = y[i] + dt*(A31*k1[i] + A32*k2[i]);
        odef(z, k3, w1f, w2f, b1v, b2v, ldsT, m, g);
        #pragma unroll
        for (int i=0;i<16;++i) z[i] = y[i] + dt*(A41*k1[i] + A42*k2[i] + A43*k3[i]);
        odef(z, k4, w1f, w2f, b1v, b2v, ldsT, m, g);
        #pragma unroll
        for (int i=0;i<16;++i) z[i] = y[i] + dt*(A51*k1[i] + A52*k2[i] + A53*k3[i] + A54*k4[i]);
        odef(z, k5, w1f, w2f, b1v, b2v, ldsT, m, g);
        #pragma unroll
        for (int i=0;i<16;++i) z[i] = y[i] + dt*(A61*k1[i] + A62*k2[i] + A63*k3[i] + A64*k4[i] + A65*k5[i]);
        odef(z, k6, w1f, w2f, b1v, b2v, ldsT, m, g);
        #pragma unroll
        for (int i=0;i<16;++i) y[i] = y[i] + dt*(B1*k1[i] + B3*k3[i] + B4*k4[i] + B5*k5[i] + B6*k6[i]);

        if ((step & 3) == 3){
            const int e = step >> 2;
            float* o = out + ((size_t)e*16384 + row0) * 64;
            #pragma unroll
            for (int q=0; q<4; ++q)
                #pragma unroll
                for (int t=0; t<4; ++t)
                    o[(4*g+q)*64 + m + 16*t] = y[q*4+t];
        }
    }
}

extern "C" void kernel_launch(void* const* d_in, const int* in_sizes, int n_in,
                              void* d_out, int out_size, void* d_ws, size_t ws_size,
                              hipStream_t stream)
{
    (void)in_sizes; (void)n_in; (void)out_size; (void)d_ws; (void)ws_size;
    const float* init_pos = (const float*)d_in[0];
    const float* W1 = (const float*)d_in[1];
    const float* b1 = (const float*)d_in[2];
    const float* W2 = (const float*)d_in[3];
    const float* b2 = (const float*)d_in[4];
    float* out = (float*)d_out;

    hipLaunchKernelGGL(ode_dopri5_kernel, dim3(256), dim3(256), 0, stream,
                       init_pos, W1, b1, W2, b2, out);
}

// Round 2
// 102.456 us; speedup vs baseline: 1.8371x; 1.8371x over previous
//
#include <hip/hip_runtime.h>
#include <stdint.h>

// ODE: y' = tanh(y@W1+b1)@W2+b2, dopri5 fixed-step (dt=0.05, 20 steps, out every 4).
// Pure-register formulation: batch = MFMA N-dim (16 cols), features/hidden = M rows.
//   layer1: h^T = W1^T . z^T   layer2: k^T = W2^T . h^T
// With the common A/B k-slot bijection phi(g,r) = (r<4 ? 4g+r : 16+4g+(r-4)),
// each layer's C-layout output IS the next layer's B-fragment after a per-lane
// cvt_pk_bf16 repack: no LDS, no cross-lane ops, no barriers in the main loop.

typedef __attribute__((ext_vector_type(8))) short short8;   // 8 bf16 (4 VGPRs)
typedef __attribute__((ext_vector_type(4))) float f32x4;

union U8 { uint32_t u[4]; short8 s; };

__device__ __forceinline__ uint32_t cvt_pk_bf16(float a, float b){
    uint32_t r;
    asm("v_cvt_pk_bf16_f32 %0, %1, %2" : "=v"(r) : "v"(a), "v"(b));
    return r;
}

__device__ __forceinline__ float fast_tanh(float x){
    // tanh(x) = 1 - 2/(1+e^{2x});  v_exp_f32 computes 2^x
    float e = __builtin_amdgcn_exp2f(x * 2.885390081777927f);   // 2*log2(e)
    float r = __builtin_amdgcn_rcpf(1.0f + e);
    return __builtin_fmaf(-2.0f, r, 1.0f);
}

// One f-eval, fully in registers.
// z, kout: C-layout f32x4[4]; z[dt][q] = state[batch=m][feature = dt*16+4*g+q].
__device__ __forceinline__ void odef(
    const f32x4 (&z)[4], f32x4 (&kout)[4],
    const short8 (&a1)[8][2], const short8 (&a2)[4][4],
    const f32x4 (&b1v)[8], const f32x4 (&b2v)[4])
{
    // repack z (C-layout) -> B-fragments, pure per-lane
    short8 zb[2];
    #pragma unroll
    for (int kc=0; kc<2; ++kc){
        U8 u;
        u.u[0] = cvt_pk_bf16(z[2*kc  ][0], z[2*kc  ][1]);
        u.u[1] = cvt_pk_bf16(z[2*kc  ][2], z[2*kc  ][3]);
        u.u[2] = cvt_pk_bf16(z[2*kc+1][0], z[2*kc+1][1]);
        u.u[3] = cvt_pk_bf16(z[2*kc+1][2], z[2*kc+1][3]);
        zb[kc] = u.s;
    }

    // layer 1: h^T = tanh(W1^T z^T + b1)
    f32x4 hreg[8];
    #pragma unroll
    for (int nt=0; nt<8; ++nt){
        f32x4 acc = b1v[nt];
        acc = __builtin_amdgcn_mfma_f32_16x16x32_bf16(a1[nt][0], zb[0], acc, 0,0,0);
        acc = __builtin_amdgcn_mfma_f32_16x16x32_bf16(a1[nt][1], zb[1], acc, 0,0,0);
        #pragma unroll
        for (int q=0; q<4; ++q) hreg[nt][q] = fast_tanh(acc[q]);
    }

    // repack h -> B-fragments
    short8 hb[4];
    #pragma unroll
    for (int kc=0; kc<4; ++kc){
        U8 u;
        u.u[0] = cvt_pk_bf16(hreg[2*kc  ][0], hreg[2*kc  ][1]);
        u.u[1] = cvt_pk_bf16(hreg[2*kc  ][2], hreg[2*kc  ][3]);
        u.u[2] = cvt_pk_bf16(hreg[2*kc+1][0], hreg[2*kc+1][1]);
        u.u[3] = cvt_pk_bf16(hreg[2*kc+1][2], hreg[2*kc+1][3]);
        hb[kc] = u.s;
    }

    // layer 2: k^T = W2^T h^T + b2
    #pragma unroll
    for (int dt=0; dt<4; ++dt){
        f32x4 acc = b2v[dt];
        #pragma unroll
        for (int kc=0; kc<4; ++kc)
            acc = __builtin_amdgcn_mfma_f32_16x16x32_bf16(a2[dt][kc], hb[kc], acc, 0,0,0);
        kout[dt] = acc;
    }
}

__global__ __launch_bounds__(256, 1)
void ode_dopri5_kernel(const float* __restrict__ init_pos,
                       const float* __restrict__ W1, const float* __restrict__ b1,
                       const float* __restrict__ W2, const float* __restrict__ b2,
                       float* __restrict__ out)
{
    __shared__ __align__(16) float lds_w[64*128];   // 32 KB, init-only (W1 then W2)

    const int tid  = threadIdx.x;
    const int wave = tid >> 6;
    const int lane = tid & 63;
    const int m = lane & 15;     // batch within the wave's 16-row tile
    const int g = lane >> 4;

    // ---- stage W1 (f32, coalesced) and build W1^T A-fragments ----
    {
        const f32x4* s = (const f32x4*)W1;
        f32x4* d = (f32x4*)lds_w;
        #pragma unroll
        for (int i=0; i<8; ++i) d[tid + 256*i] = s[tid + 256*i];
    }
    __syncthreads();

    short8 a1[8][2];   // a1[nt][kc]: A-frag of W1^T, rows n = nt*16+m, k = feature
    #pragma unroll
    for (int nt=0; nt<8; ++nt)
        #pragma unroll
        for (int kc=0; kc<2; ++kc){
            U8 u;
            #pragma unroll
            for (int j=0; j<4; ++j){
                int kb = kc*32 + ((j<2) ? (4*g + 2*j) : (16 + 4*g + 2*(j-2)));
                u.u[j] = cvt_pk_bf16(lds_w[(kb  )*128 + nt*16 + m],
                                     lds_w[(kb+1)*128 + nt*16 + m]);
            }
            a1[nt][kc] = u.s;
        }
    __syncthreads();

    // ---- stage W2 and build W2^T A-fragments ----
    {
        const f32x4* s = (const f32x4*)W2;
        f32x4* d = (f32x4*)lds_w;
        #pragma unroll
        for (int i=0; i<8; ++i) d[tid + 256*i] = s[tid + 256*i];
    }
    __syncthreads();

    short8 a2[4][4];   // a2[dt][kc]: A-frag of W2^T, rows d = dt*16+m, k = hidden n
    #pragma unroll
    for (int dt=0; dt<4; ++dt)
        #pragma unroll
        for (int kc=0; kc<4; ++kc){
            U8 u;
            #pragma unroll
            for (int j=0; j<4; ++j){
                int nb = kc*32 + ((j<2) ? (4*g + 2*j) : (16 + 4*g + 2*(j-2)));
                u.u[j] = cvt_pk_bf16(lds_w[(nb  )*64 + dt*16 + m],
                                     lds_w[(nb+1)*64 + dt*16 + m]);
            }
            a2[dt][kc] = u.s;
        }

    // ---- bias vectors in C-layout: element q <-> row 4g+q ----
    f32x4 b1v[8], b2v[4];
    #pragma unroll
    for (int nt=0; nt<8; ++nt)
        b1v[nt] = *(const f32x4*)(b1 + nt*16 + 4*g);
    #pragma unroll
    for (int dt=0; dt<4; ++dt)
        b2v[dt] = *(const f32x4*)(b2 + dt*16 + 4*g);

    // ---- load y in C-layout: y[dt][q] = init_pos[row0+m][dt*16+4g+q] ----
    const int row0 = (blockIdx.x*4 + wave) * 16;
    f32x4 y[4];
    #pragma unroll
    for (int dt=0; dt<4; ++dt)
        y[dt] = *(const f32x4*)(init_pos + (size_t)(row0 + m)*64 + dt*16 + 4*g);

    // Dopri5 coefficients
    const float dt_h = 0.05f;
    const float A21 = 0.2f;
    const float A31 = 0.075f,             A32 = 0.225f;
    const float A41 = 44.f/45.f,  A42 = -56.f/15.f,    A43 = 32.f/9.f;
    const float A51 = 19372.f/6561.f, A52 = -25360.f/2187.f, A53 = 64448.f/6561.f, A54 = -212.f/729.f;
    const float A61 = 9017.f/3168.f,  A62 = -355.f/33.f,     A63 = 46732.f/5247.f, A64 = 49.f/176.f, A65 = -5103.f/18656.f;
    const float B1  = 35.f/384.f, B3 = 500.f/1113.f, B4 = 125.f/192.f, B5 = -2187.f/6784.f, B6 = 11.f/84.f;

    f32x4 k1[4], k2[4], k3[4], k4[4], k5[4], k6[4], z[4];

    for (int step=0; step<20; ++step){
        odef(y, k1, a1, a2, b1v, b2v);
        #pragma unroll
        for (int i=0;i<4;++i) z[i] = y[i] + dt_h*(A21*k1[i]);
        odef(z, k2, a1, a2, b1v, b2v);
        #pragma unroll
        for (int i=0;i<4;++i) z[i] = y[i] + dt_h*(A31*k1[i] + A32*k2[i]);
        odef(z, k3, a1, a2, b1v, b2v);
        #pragma unroll
        for (int i=0;i<4;++i) z[i] = y[i] + dt_h*(A41*k1[i] + A42*k2[i] + A43*k3[i]);
        odef(z, k4, a1, a2, b1v, b2v);
        #pragma unroll
        for (int i=0;i<4;++i) z[i] = y[i] + dt_h*(A51*k1[i] + A52*k2[i] + A53*k3[i] + A54*k4[i]);
        odef(z, k5, a1, a2, b1v, b2v);
        #pragma unroll
        for (int i=0;i<4;++i) z[i] = y[i] + dt_h*(A61*k1[i] + A62*k2[i] + A63*k3[i] + A64*k4[i] + A65*k5[i]);
        odef(z, k6, a1, a2, b1v, b2v);
        #pragma unroll
        for (int i=0;i<4;++i) y[i] = y[i] + dt_h*(B1*k1[i] + B3*k3[i] + B4*k4[i] + B5*k5[i] + B6*k6[i]);

        if ((step & 3) == 3){
            const int e = step >> 2;
            float* o = out + (size_t)e*16384*64 + (size_t)(row0 + m)*64;
            #pragma unroll
            for (int dt=0; dt<4; ++dt)
                *(f32x4*)(o + dt*16 + 4*g) = y[dt];
        }
    }
}

extern "C" void kernel_launch(void* const* d_in, const int* in_sizes, int n_in,
                              void* d_out, int out_size, void* d_ws, size_t ws_size,
                              hipStream_t stream)
{
    (void)in_sizes; (void)n_in; (void)out_size; (void)d_ws; (void)ws_size;
    const float* init_pos = (const float*)d_in[0];
    const float* W1 = (const float*)d_in[1];
    const float* b1 = (const float*)d_in[2];
    const float* W2 = (const float*)d_in[3];
    const float* b2 = (const float*)d_in[4];
    float* out = (float*)d_out;

    hipLaunchKernelGGL(ode_dopri5_kernel, dim3(256), dim3(256), 0, stream,
                       init_pos, W1, b1, W2, b2, out);
}